// Round 17
// baseline (98.934 us; speedup 1.0000x reference)
//
#include <hip/hip_runtime.h>

// MHA forward, MI355X gfx950.
// R17: QKV GEMM goes 8-wave (512 thr) on the same 128x128 tile — wave = 64x32
//      output, 16 waves/CU (4/SIMD) vs 8 — attacking exposed ds_read/MFMA
//      latency with stream count. Out-proj keeps proven 256-thr mapping.
//      attn (R16 uniform dual-group) / prep unchanged.

#define SEQ   2048
#define DMODEL 1024
#define NH    16
#define HD    64
#define MROWS 4096   // b*t = 2*2048

typedef __attribute__((ext_vector_type(4))) float f32x4;
typedef __attribute__((ext_vector_type(16))) float f32x16;
typedef __attribute__((ext_vector_type(8))) short short8;
typedef __attribute__((ext_vector_type(4))) unsigned int u32x4;

#define MFMA16(a, b, c) __builtin_amdgcn_mfma_f32_16x16x32_bf16((a), (b), (c), 0, 0, 0)
#define MFMA32(a, b, c) __builtin_amdgcn_mfma_f32_32x32x16_bf16((a), (b), (c), 0, 0, 0)

__device__ __forceinline__ unsigned short f2bf(float f) {
  union { float f; unsigned u; } v; v.f = f;
  return (unsigned short)((v.u + 0x7fffu + ((v.u >> 16) & 1u)) >> 16);
}

__device__ __forceinline__ float exp2x(float x) {
#if __has_builtin(__builtin_amdgcn_exp2f)
  return __builtin_amdgcn_exp2f(x);
#else
  float r; asm("v_exp_f32 %0, %1" : "=v"(r) : "v"(x)); return r;
#endif
}

__device__ __forceinline__ unsigned cvt_pk(float lo, float hi) {
  unsigned r;
  asm volatile("v_cvt_pk_bf16_f32 %0, %1, %2" : "=v"(r) : "v"(lo), "v"(hi));
  return r;
}

// v_permlane32_swap: a' = [a.lo | b.lo-in-hi-lanes], b' = [a.hi-in-lo-lanes | b.hi]
__device__ __forceinline__ void pls(unsigned& a, unsigned& b) {
  asm("v_permlane32_swap_b32 %0, %1" : "+v"(a), "+v"(b));
}

__device__ __forceinline__ short8 as_short8(u32x4 v) {
  union { u32x4 u; short8 s; } x; x.u = v; return x.s;
}

__device__ __forceinline__ f32x4 zero4() {
  f32x4 z; z[0] = 0.f; z[1] = 0.f; z[2] = 0.f; z[3] = 0.f; return z;
}

// async global->LDS, 16B per lane, linear dest (wave base + lane*16)
__device__ __forceinline__ void async16(const void* g, void* l) {
  __builtin_amdgcn_global_load_lds(
      (const __attribute__((address_space(1))) unsigned int*)g,
      (__attribute__((address_space(3))) unsigned int*)l, 16, 0, 0);
}

// ---------------- prep: x->bf16 (blocks 0..2047) + 4x W transpose (2048..3071) ----------------
__global__ __launch_bounds__(256) void prep(
    const float* __restrict__ x, const float* __restrict__ Wq,
    const float* __restrict__ Wk, const float* __restrict__ Wv,
    const float* __restrict__ Wo, unsigned short* __restrict__ xb,
    unsigned short* __restrict__ Wt, unsigned short* __restrict__ WoT) {
  __shared__ unsigned short tile[64][65];
  const int bx = blockIdx.x;
  if (bx < 2048) {
    int i = bx * 256 + threadIdx.x;            // handles 8 elements
    const float4* p = (const float4*)x;
    float4 a = p[2 * i];
    float4 b = p[2 * i + 1];
    short8 o;
    o[0] = (short)f2bf(a.x); o[1] = (short)f2bf(a.y);
    o[2] = (short)f2bf(a.z); o[3] = (short)f2bf(a.w);
    o[4] = (short)f2bf(b.x); o[5] = (short)f2bf(b.y);
    o[6] = (short)f2bf(b.z); o[7] = (short)f2bf(b.w);
    *(short8*)&xb[(size_t)i * 8] = o;
    return;
  }
  const int id2 = bx - 2048;
  const int m = id2 >> 8;                      // which matrix
  const float* W = (m == 0) ? Wq : (m == 1) ? Wk : (m == 2) ? Wv : Wo;
  unsigned short* D = (m == 3) ? WoT : Wt + (size_t)m * 1024 * 1024;
  const int tid = id2 & 255;
  const int kb = (tid >> 4) * 64, nb = (tid & 15) * 64;
  const int t = threadIdx.x;
  const int tx = t & 63, ty = t >> 6;          // ty 0..3
#pragma unroll
  for (int rr = 0; rr < 16; rr++) {
    int r = ty * 16 + rr;
    tile[r][tx] = f2bf(W[(size_t)(kb + r) * 1024 + nb + tx]);
  }
  __syncthreads();
#pragma unroll
  for (int rr = 0; rr < 16; rr++) {
    int r = ty * 16 + rr;
    D[(size_t)(nb + r) * 1024 + kb + tx] = tile[tx][r];
  }
}

// ---------------- GEMM: C[M,N] = A[M,1024] * Bt[N,1024]^T ----------------
// R17: MODE 0 runs 512 thr / 8 waves, wave = 64x32 of the 128x128 tile
//      (wr=w>>2, wc=w&3, 4 m-frags x 2 n-frags) -> 16 waves/CU at 64KB LDS.
//      MODE 1 keeps the R12 256-thr mapping (BM=64, wave 32x64).
// Both: paired k-windows, 2x2 LDS buffers, counted vmcnt, chunk-XOR swizzle,
//       XCD swizzle.
template <int MODE>
__global__ __launch_bounds__(MODE == 0 ? 512 : 256) void gemm_bt(
    const unsigned short* __restrict__ A, const unsigned short* __restrict__ Bt,
    unsigned short* __restrict__ Qo, unsigned short* __restrict__ Ko,
    unsigned short* __restrict__ Vo, float* __restrict__ out,
    const float* __restrict__ bo) {
  constexpr int K = 1024;
  constexpr int NTHR = (MODE == 0) ? 512 : 256;
  constexpr int BM = (MODE == 0) ? 128 : 64;
  constexpr int WCW = (MODE == 0) ? 4 : 2;     // waves along cols
  constexpr int MF = (MODE == 0) ? 4 : 2;      // m-frags per wave
  constexpr int NF = 8 / WCW;                  // n-frags per wave (2 or 4)
  constexpr int NW = K / 64;                   // 16 windows of 2 subtiles
  constexpr int ASZ = BM * 32;
  constexpr int BSZ = 128 * 32;
  __shared__ __align__(16) unsigned short smem[4 * ASZ + 4 * BSZ];
  unsigned short* Asb = smem;
  unsigned short* Bsb = smem + 4 * ASZ;
  const int t = threadIdx.x;
  const int lane = t & 63;
  const int w = t >> 6;
  const int lr = lane & 15, kf = lane >> 4;
  const int wr = w / WCW, wc = w % WCW;

  const int nwg = gridDim.x * gridDim.y;
  const int id = blockIdx.y * gridDim.x + blockIdx.x;
  const int swz = (id & 7) * (nwg >> 3) + (id >> 3);
  const int bx = swz % gridDim.x, by = swz / gridDim.x;

  const int rowbase = bx * BM;
  const int colbase = by * 128;

  const unsigned short* Ab = A + (size_t)rowbase * K;
  const unsigned short* Bb = Bt + (size_t)colbase * K;

  f32x4 acc[MF][NF];
#pragma unroll
  for (int m = 0; m < MF; m++)
#pragma unroll
    for (int n = 0; n < NF; n++) acc[m][n] = zero4();

  // stage window wi (subtiles 2wi, 2wi+1). physical chunk f holds logical
  // chunk c = f ^ ((f>>3)&3); reads XOR back (both-sides involution).
  auto stage = [&](int buf, int wi) {
#pragma unroll
    for (int sub = 0; sub < 2; sub++) {
      int k0 = (2 * wi + sub) * 32;
      unsigned short* Ad = Asb + ((size_t)buf * 2 + sub) * ASZ;
      unsigned short* Bd = Bsb + ((size_t)buf * 2 + sub) * BSZ;
#pragma unroll
      for (int i = 0; i < BM * 4 / NTHR; i++) {   // == 1
        int f = i * NTHR + t;
        int c = f ^ ((f >> 3) & 3);
        int row = c >> 2;
        int col = (c & 3) << 3;
        async16(Ab + (size_t)row * K + k0 + col, (char*)Ad + (size_t)f * 16);
      }
#pragma unroll
      for (int i = 0; i < 512 / NTHR; i++) {      // 1 or 2
        int f = i * NTHR + t;
        int c = f ^ ((f >> 3) & 3);
        int row = c >> 2;
        int col = (c & 3) << 3;
        async16(Bb + (size_t)row * K + k0 + col, (char*)Bd + (size_t)f * 16);
      }
    }
  };

  auto compute = [&](int buf, int sub) {
    const unsigned short* As = Asb + ((size_t)buf * 2 + sub) * ASZ;
    const unsigned short* Bs = Bsb + ((size_t)buf * 2 + sub) * BSZ;
    short8 av[MF], bv[NF];
#pragma unroll
    for (int m = 0; m < MF; m++) {
      int row = wr * (MF * 16) + m * 16 + lr;
      int idx = (row * 32 + kf * 8) ^ (((row >> 1) & 3) << 3);
      av[m] = *(const short8*)&As[idx];
    }
#pragma unroll
    for (int n = 0; n < NF; n++) {
      int row = wc * (NF * 16) + n * 16 + lr;
      int idx = (row * 32 + kf * 8) ^ (((row >> 1) & 3) << 3);
      bv[n] = *(const short8*)&Bs[idx];
    }
    __builtin_amdgcn_s_setprio(1);
#pragma unroll
    for (int m = 0; m < MF; m++)
#pragma unroll
      for (int n = 0; n < NF; n++) acc[m][n] = MFMA16(av[m], bv[n], acc[m][n]);
    __builtin_amdgcn_s_setprio(0);
  };

  stage(0, 0);
  int cur = 0;

  // per-thread async16 per stage: 2*(1 + 512/NTHR) -> MODE0: 4, MODE1: 6
  for (int wi = 0; wi < NW; wi++) {
    if (wi + 1 < NW) {
      stage(cur ^ 1, wi + 1);
      if constexpr (MODE == 0) asm volatile("s_waitcnt vmcnt(4)" ::: "memory");
      else                     asm volatile("s_waitcnt vmcnt(6)" ::: "memory");
    } else {
      asm volatile("s_waitcnt vmcnt(0)" ::: "memory");
    }
    __builtin_amdgcn_s_barrier();

    compute(cur, 0);
    compute(cur, 1);

    __builtin_amdgcn_s_barrier();
    cur ^= 1;
  }

  // Epilogue. C/D layout: col = lane&15, row = (lane>>4)*4 + i  [m89-verified]
  if constexpr (MODE == 0) {
    if (colbase < 2048) {
      const int selq = colbase >> 10;              // 0=Q 1=K
      unsigned short* dst = selq ? Ko : Qo;
      const float sc = selq ? 1.0f : 0.18033688011112042f;  // 0.125*log2e into Q
#pragma unroll
      for (int n = 0; n < NF; n++) {
        int c = colbase + wc * (NF * 16) + n * 16 + lr;
        int hh = (c >> 6) & 15;
        int dd = c & 63;
#pragma unroll
        for (int m = 0; m < MF; m++) {
          int r0 = rowbase + wr * (MF * 16) + m * 16 + kf * 4;
#pragma unroll
          for (int i = 0; i < 4; i++) {
            int r = r0 + i;
            int bi = r >> 11;
            int tq = r & 2047;
            dst[((size_t)(bi * NH + hh) * SEQ + tq) * HD + dd] = f2bf(acc[m][n][i] * sc);
          }
        }
      }
    } else {
      // V block: transpose tile in LDS (dead pipeline buffers), store V^T coalesced.
      unsigned short* tr = smem;                   // [128 col][136]
#pragma unroll
      for (int n = 0; n < NF; n++) {
        int ccol = wc * (NF * 16) + n * 16 + lr;
#pragma unroll
        for (int m = 0; m < MF; m++) {
#pragma unroll
          for (int i = 0; i < 4; i++) {
            int rrow = wr * (MF * 16) + m * 16 + kf * 4 + i;
            tr[ccol * 136 + rrow] = f2bf(acc[m][n][i]);
          }
        }
      }
      __syncthreads();
      const int bi2 = rowbase >> 11;
      const int tq0 = rowbase & 2047;
#pragma unroll
      for (int k2 = 0; k2 < 2048 / NTHR; k2++) {   // 4 iters at 512 thr
        int u = k2 * NTHR + t;                     // [col][seg of 8]
        int cc = u >> 4, seg = u & 15;
        int c = colbase + cc;
        int hh = (c >> 6) & 15, dd = c & 63;
        short8 v8 = *(const short8*)&tr[cc * 136 + seg * 8];
        *(short8*)&Vo[((size_t)(bi2 * NH + hh) * HD + dd) * SEQ + tq0 + seg * 8] = v8;
      }
    }
  } else {
#pragma unroll
    for (int n = 0; n < NF; n++) {
      int c = colbase + wc * (NF * 16) + n * 16 + lr;
      float bias = bo[c];
#pragma unroll
      for (int m = 0; m < MF; m++) {
        int r0 = rowbase + wr * (MF * 16) + m * 16 + kf * 4;
#pragma unroll
        for (int i = 0; i < 4; i++) {
          out[(size_t)(r0 + i) * 1024 + c] = acc[m][n][i] + bias;
        }
      }
    }
  }
}

// ---------------- flash attention (R16: uniform blocks, 2 q-tiles, 2 wave groups) ----------
__global__ __launch_bounds__(512) void attn_fwd(
    const unsigned short* __restrict__ Q, const unsigned short* __restrict__ K,
    const unsigned short* __restrict__ Vt, unsigned short* __restrict__ ctx) {
  const int bh = blockIdx.x;
  const int y = blockIdx.y;                     // 0..7
  const int qa = 15 - y, qb = y;
  const int bi = bh >> 4, hh = bh & 15;
  const int t = threadIdx.x, lane = t & 63, w = t >> 6;
  const int g = w >> 2, wl = w & 3, tg = t & 255;
  const int qc = lane & 31, hi = lane >> 5;

  // [group][dbuf][sub]
  __shared__ __align__(16) unsigned short Ks[2][2][2][4096];
  __shared__ __align__(16) unsigned short Vs[2][2][2][4096];

  const unsigned short* Qb = Q + (size_t)bh * SEQ * HD;
  const unsigned short* Kb = K + (size_t)bh * SEQ * HD;
  const unsigned short* Vb = Vt + (size_t)bh * HD * SEQ;

  const int qrowA = qa * 128 + wl * 32;
  const int qrowB = qb * 128 + wl * 32;
  const int ktmaxA = 2 * qa + (wl >> 1);
  const int ktmaxB = 2 * qb + (wl >> 1);

  short8 qvA[4], qvB[4];
#pragma unroll
  for (int c = 0; c < 4; c++)
    qvA[c] = *(const short8*)&Qb[(size_t)(qrowA + qc) * HD + c * 16 + hi * 8];
  if (g == 1) {
#pragma unroll
    for (int c = 0; c < 4; c++)
      qvB[c] = *(const short8*)&Qb[(size_t)(qrowB + qc) * HD + c * 16 + hi * 8];
  }

  f32x16 oA0, oA1, oB0, oB1;
#pragma unroll
  for (int i = 0; i < 16; i++) { oA0[i] = 0.f; oA1[i] = 0.f; oB0[i] = 0.f; oB1[i] = 0.f; }
  float lA = 0.f, lB = 0.f;

  auto pairAt = [&](int i, bool& useB, int& p) -> bool {
    if (g == 0) { useB = false; p = i; return i < 8; }
    if (i <= qb) { useB = true; p = i; return true; }
    useB = false; p = 8 + (i - qb - 1); return true;
  };

  auto stage = [&](int buf, int p) {
#pragma unroll
    for (int sub = 0; sub < 2; sub++) {
      int kt = 2 * p + sub;
#pragma unroll
      for (int i2 = 0; i2 < 2; i2++) {
        int f = i2 * 256 + tg;
        int c = f ^ ((f >> 3) & 7);
        async16(Kb + (size_t)kt * 64 * HD + (size_t)c * 8,
                (char*)&Ks[g][buf][sub][0] + (size_t)f * 16);
        int d = c >> 3, ko = (c & 7) << 3;
        async16(Vb + (size_t)d * SEQ + (size_t)kt * 64 + ko,
                (char*)&Vs[g][buf][sub][0] + (size_t)f * 16);
      }
    }
  };

  auto qk = [&](const unsigned short* Kt, const short8* qv, f32x16& s0, f32x16& s1) {
#pragma unroll
    for (int i = 0; i < 16; i++) { s0[i] = 0.f; s1[i] = 0.f; }
    __builtin_amdgcn_s_setprio(1);
#pragma unroll
    for (int c = 0; c < 4; c++) {
      int i0 = (qc * 64 + c * 16 + hi * 8) ^ ((qc & 7) << 3);
      s0 = MFMA32(*(const short8*)&Kt[i0], qv[c], s0);
      int r1 = 32 + qc;
      int i1 = (r1 * 64 + c * 16 + hi * 8) ^ ((r1 & 7) << 3);
      s1 = MFMA32(*(const short8*)&Kt[i1], qv[c], s1);
    }
    __builtin_amdgcn_s_setprio(0);
  };

  auto maskit = [&](f32x16& s0, f32x16& s1, int kt, int qrow) {
    const int qg = qrow + qc;
#pragma unroll
    for (int reg = 0; reg < 16; reg++) {
      int rloc = (reg & 3) + 8 * (reg >> 2) + 4 * hi;
      int kg = kt * 64 + rloc;
      if (kg > qg) s0[reg] = -1e30f;
      if (kg + 32 > qg) s1[reg] = -1e30f;
    }
  };

  auto smpack = [&](const f32x16& s0, const f32x16& s1, unsigned* w0, unsigned* w1,
                    float& lacc) {
    float psA = 0.f, psB = 0.f;
#pragma unroll
    for (int j = 0; j < 8; j++) {
      float a0 = exp2x(s0[2 * j]), b0 = exp2x(s0[2 * j + 1]);
      float a1 = exp2x(s1[2 * j]), b1 = exp2x(s1[2 * j + 1]);
      psA += a0 + b0;
      psB += a1 + b1;
      w0[j] = cvt_pk(a0, b0);
      w1[j] = cvt_pk(a1, b1);
    }
    lacc += psA + psB;
  };

  auto pv = [&](const unsigned short* Vtile, unsigned* w0, unsigned* w1,
                f32x16& o0, f32x16& o1) {
    __builtin_amdgcn_s_setprio(1);
#pragma unroll
    for (int h2 = 0; h2 < 2; h2++) {
      unsigned* pw = h2 ? w1 : w0;
#pragma unroll
      for (int cc = 0; cc < 2; cc++) {
        unsigned a0 = pw[cc * 4 + 0], b0 = pw[cc * 4 + 2];
        unsigned a1 = pw[cc * 4 + 1], b1 = pw[cc * 4 + 3];
        pls(a0, b0);
        pls(a1, b1);
        u32x4 pf; pf[0] = a0; pf[1] = a1; pf[2] = b0; pf[3] = b1;
        short8 pfrag = as_short8(pf);
        int c2 = h2 * 2 + cc;
        int ia = (qc * 64 + c2 * 16 + hi * 8) ^ ((qc & 7) << 3);
        o0 = MFMA32(*(const short8*)&Vtile[ia], pfrag, o0);
        int rb = 32 + qc;
        int ib = (rb * 64 + c2 * 16 + hi * 8) ^ ((rb & 7) << 3);
        o1 = MFMA32(*(const short8*)&Vtile[ib], pfrag, o1);
      }
    }
    __builtin_amdgcn_s_setprio(0);
  };

  auto do_pair = [&](int cur, int p, const short8* qv, int ktmax, int qrow,
                     f32x16& o0, f32x16& o1, float& lacc) {
    const bool v0 = (2 * p <= ktmax);
    const bool v1 = (2 * p + 1 <= ktmax);
    f32x16 sA0, sA1, sB0, sB1;
    if (v0) qk(&Ks[g][cur][0][0], qv, sA0, sA1);
    if (v1) qk(&Ks[g][cur][1][0], qv, sB0, sB1);
    if (v0 && 2 * p == ktmax)     maskit(sA0, sA1, 2 * p, qrow);
    if (v1 && 2 * p + 1 == ktmax) maskit(sB0, sB1, 2 * p + 1, qrow);
    unsigned w0A[8], w1A[8], w0B[8], w1B[8];
    if (v0) smpack(sA0, sA1, w0A, w1A, lacc);
    if (v1) smpack(sB0, sB1, w0B, w1B, lacc);
    if (v0) pv(&Vs[g][cur][0][0], w0A, w1A, o0, o1);
    if (v1) pv(&Vs[g][cur][1][0], w0B, w1B, o0, o1);
  };

  {
    bool ub; int p0;
    if (pairAt(0, ub, p0)) stage(0, p0);
  }
  int cur = 0;

  for (int i = 0; i < 9; i++) {
    bool ubn; int pn;
    const bool hasn = (i + 1 < 9) && pairAt(i + 1, ubn, pn);
    if (hasn) {
      stage(cur ^ 1, pn);
      asm volatile("s_waitcnt vmcnt(8)" ::: "memory");
    } else {
      asm volatile("s_waitcnt vmcnt(0)" ::: "memory");
    }
    __builtin_amdgcn_s_barrier();

    bool ub; int p;
    if (pairAt(i, ub, p)) {
      if (ub) do_pair(cur, p, qvB, ktmaxB, qrowB, oB0, oB1, lB);
      else    do_pair(cur, p, qvA, ktmaxA, qrowA, oA0, oA1, lA);
    }

    __builtin_amdgcn_s_barrier();
    cur ^= 1;
  }

  // ---- epilogue ----
  float* ex = (float*)&Ks[0][0][0][0];
  float* lex = ex + 128 * 65;

  float lApart = lA + __shfl_xor(lA, 32);

  __builtin_amdgcn_s_barrier();    // staging LDS dead
  if (g == 1) {
    const int row = wl * 32 + qc;
#pragma unroll
    for (int gi = 0; gi < 4; gi++) {
#pragma unroll
      for (int jj = 0; jj < 4; jj++) {
        ex[row * 65 + 8 * gi + 4 * hi + jj] = oA0[4 * gi + jj];
        ex[row * 65 + 32 + 8 * gi + 4 * hi + jj] = oA1[4 * gi + jj];
      }
    }
    if (hi == 0) lex[row] = lApart;
  }
  __builtin_amdgcn_s_barrier();

  if (g == 0) {
    const int row = wl * 32 + qc;
#pragma unroll
    for (int gi = 0; gi < 4; gi++) {
#pragma unroll
      for (int jj = 0; jj < 4; jj++) {
        oA0[4 * gi + jj] += ex[row * 65 + 8 * gi + 4 * hi + jj];
        oA1[4 * gi + jj] += ex[row * 65 + 32 + 8 * gi + 4 * hi + jj];
      }
    }
    float l = lApart + lex[row];
    float inv = 1.0f / l;
    const size_t rowoff = ((size_t)bi * SEQ + qrowA + qc) * DMODEL + hh * HD;
#pragma unroll
    for (int gi = 0; gi < 4; gi++) {
      unsigned pa = cvt_pk(oA0[4 * gi] * inv, oA0[4 * gi + 1] * inv);
      unsigned pb = cvt_pk(oA0[4 * gi + 2] * inv, oA0[4 * gi + 3] * inv);
      uint2 vv; vv.x = pa; vv.y = pb;
      *(uint2*)&ctx[rowoff + 8 * gi + 4 * hi] = vv;
      unsigned pc = cvt_pk(oA1[4 * gi] * inv, oA1[4 * gi + 1] * inv);
      unsigned pd = cvt_pk(oA1[4 * gi + 2] * inv, oA1[4 * gi + 3] * inv);
      uint2 ww; ww.x = pc; ww.y = pd;
      *(uint2*)&ctx[rowoff + 32 + 8 * gi + 4 * hi] = ww;
    }
  } else {
    float l = lB + __shfl_xor(lB, 32);
    float inv = 1.0f / l;
    const size_t rowoff = ((size_t)bi * SEQ + qrowB + qc) * DMODEL + hh * HD;
#pragma unroll
    for (int gi = 0; gi < 4; gi++) {
      unsigned pa = cvt_pk(oB0[4 * gi] * inv, oB0[4 * gi + 1] * inv);
      unsigned pb = cvt_pk(oB0[4 * gi + 2] * inv, oB0[4 * gi + 3] * inv);
      uint2 vv; vv.x = pa; vv.y = pb;
      *(uint2*)&ctx[rowoff + 8 * gi + 4 * hi] = vv;
      unsigned pc = cvt_pk(oB1[4 * gi] * inv, oB1[4 * gi + 1] * inv);
      unsigned pd = cvt_pk(oB1[4 * gi + 2] * inv, oB1[4 * gi + 3] * inv);
      uint2 ww; ww.x = pc; ww.y = pd;
      *(uint2*)&ctx[rowoff + 32 + 8 * gi + 4 * hi] = ww;
    }
  }
}

// ---------------- launch ----------------
extern "C" void kernel_launch(void* const* d_in, const int* in_sizes, int n_in,
                              void* d_out, int out_size, void* d_ws, size_t ws_size,
                              hipStream_t stream) {
  const float* x  = (const float*)d_in[0];
  const float* Wq = (const float*)d_in[1];
  const float* Wk = (const float*)d_in[2];
  const float* Wv = (const float*)d_in[3];
  const float* Wo = (const float*)d_in[4];
  const float* bo = (const float*)d_in[5];
  float* out = (float*)d_out;

  unsigned short* xb   = (unsigned short*)d_ws;                 // 4M elems
  unsigned short* Wt   = xb + (size_t)MROWS * DMODEL;           // 3M (Wq^T|Wk^T|Wv^T)
  unsigned short* WoT  = Wt + (size_t)3 * 1024 * 1024;          // 1M
  unsigned short* Qb   = WoT + (size_t)1024 * 1024;             // 4M
  unsigned short* Kb   = Qb + (size_t)MROWS * DMODEL;           // 4M
  unsigned short* Vb   = Kb + (size_t)MROWS * DMODEL;           // 4M  V^T [b,h,d,t]
  unsigned short* ctxb = Vb + (size_t)MROWS * DMODEL;           // 4M

  prep<<<3072, 256, 0, stream>>>(x, Wq, Wk, Wv, Wo, xb, Wt, WoT);

  gemm_bt<0><<<dim3(32, 24), 512, 0, stream>>>(xb, Wt, Qb, Kb, Vb, nullptr, nullptr);
  attn_fwd<<<dim3(32, 8), 512, 0, stream>>>(Qb, Kb, Vb, ctxb);
  gemm_bt<1><<<dim3(64, 8), 256, 0, stream>>>(ctxb, WoT, nullptr, nullptr, nullptr, out, bo);
}

// Round 18
// 98.158 us; speedup vs baseline: 1.0079x; 1.0079x over previous
//
#include <hip/hip_runtime.h>

// MHA forward, MI355X gfx950.
// R18 = R16 verbatim (best measured: 98.42us). R17's 8-wave QKV split was
//      neutral-negative and is reverted. Final configuration:
//      - prep: fused x->bf16 + 4x W-transpose
//      - gemm_bt: 128-col tiles, paired 32-k windows, 2x2 LDS buffers, counted
//        vmcnt, chunk-XOR LDS swizzle, XCD swizzle, fused QKV scatter + in-LDS
//        V^T transpose epilogue (MODE 0) / bias epilogue (MODE 1)
//      - attn_fwd: uniform-work blocks (2 q-tiles, 2 wave groups, 9 windows
//        each), swapped-operand 32x32 MFMA, static exp2 softmax, permlane P
//        assembly, in-block partial combine.

#define SEQ   2048
#define DMODEL 1024
#define NH    16
#define HD    64
#define MROWS 4096   // b*t = 2*2048

typedef __attribute__((ext_vector_type(4))) float f32x4;
typedef __attribute__((ext_vector_type(16))) float f32x16;
typedef __attribute__((ext_vector_type(8))) short short8;
typedef __attribute__((ext_vector_type(4))) unsigned int u32x4;

#define MFMA16(a, b, c) __builtin_amdgcn_mfma_f32_16x16x32_bf16((a), (b), (c), 0, 0, 0)
#define MFMA32(a, b, c) __builtin_amdgcn_mfma_f32_32x32x16_bf16((a), (b), (c), 0, 0, 0)

__device__ __forceinline__ unsigned short f2bf(float f) {
  union { float f; unsigned u; } v; v.f = f;
  return (unsigned short)((v.u + 0x7fffu + ((v.u >> 16) & 1u)) >> 16);
}

__device__ __forceinline__ float exp2x(float x) {
#if __has_builtin(__builtin_amdgcn_exp2f)
  return __builtin_amdgcn_exp2f(x);
#else
  float r; asm("v_exp_f32 %0, %1" : "=v"(r) : "v"(x)); return r;
#endif
}

__device__ __forceinline__ unsigned cvt_pk(float lo, float hi) {
  unsigned r;
  asm volatile("v_cvt_pk_bf16_f32 %0, %1, %2" : "=v"(r) : "v"(lo), "v"(hi));
  return r;
}

// v_permlane32_swap: a' = [a.lo | b.lo-in-hi-lanes], b' = [a.hi-in-lo-lanes | b.hi]
__device__ __forceinline__ void pls(unsigned& a, unsigned& b) {
  asm("v_permlane32_swap_b32 %0, %1" : "+v"(a), "+v"(b));
}

__device__ __forceinline__ short8 as_short8(u32x4 v) {
  union { u32x4 u; short8 s; } x; x.u = v; return x.s;
}

__device__ __forceinline__ f32x4 zero4() {
  f32x4 z; z[0] = 0.f; z[1] = 0.f; z[2] = 0.f; z[3] = 0.f; return z;
}

// async global->LDS, 16B per lane, linear dest (wave base + lane*16)
__device__ __forceinline__ void async16(const void* g, void* l) {
  __builtin_amdgcn_global_load_lds(
      (const __attribute__((address_space(1))) unsigned int*)g,
      (__attribute__((address_space(3))) unsigned int*)l, 16, 0, 0);
}

// ---------------- prep: x->bf16 (blocks 0..2047) + 4x W transpose (2048..3071) ----------------
__global__ __launch_bounds__(256) void prep(
    const float* __restrict__ x, const float* __restrict__ Wq,
    const float* __restrict__ Wk, const float* __restrict__ Wv,
    const float* __restrict__ Wo, unsigned short* __restrict__ xb,
    unsigned short* __restrict__ Wt, unsigned short* __restrict__ WoT) {
  __shared__ unsigned short tile[64][65];
  const int bx = blockIdx.x;
  if (bx < 2048) {
    int i = bx * 256 + threadIdx.x;            // handles 8 elements
    const float4* p = (const float4*)x;
    float4 a = p[2 * i];
    float4 b = p[2 * i + 1];
    short8 o;
    o[0] = (short)f2bf(a.x); o[1] = (short)f2bf(a.y);
    o[2] = (short)f2bf(a.z); o[3] = (short)f2bf(a.w);
    o[4] = (short)f2bf(b.x); o[5] = (short)f2bf(b.y);
    o[6] = (short)f2bf(b.z); o[7] = (short)f2bf(b.w);
    *(short8*)&xb[(size_t)i * 8] = o;
    return;
  }
  const int id2 = bx - 2048;
  const int m = id2 >> 8;                      // which matrix
  const float* W = (m == 0) ? Wq : (m == 1) ? Wk : (m == 2) ? Wv : Wo;
  unsigned short* D = (m == 3) ? WoT : Wt + (size_t)m * 1024 * 1024;
  const int tid = id2 & 255;
  const int kb = (tid >> 4) * 64, nb = (tid & 15) * 64;
  const int t = threadIdx.x;
  const int tx = t & 63, ty = t >> 6;          // ty 0..3
#pragma unroll
  for (int rr = 0; rr < 16; rr++) {
    int r = ty * 16 + rr;
    tile[r][tx] = f2bf(W[(size_t)(kb + r) * 1024 + nb + tx]);
  }
  __syncthreads();
#pragma unroll
  for (int rr = 0; rr < 16; rr++) {
    int r = ty * 16 + rr;
    D[(size_t)(nb + r) * 1024 + kb + tx] = tile[tx][r];
  }
}

// ---------------- GEMM: C[M,N] = A[M,1024] * Bt[N,1024]^T ----------------
// (R12: paired k-windows, 2x2 LDS buffers, counted vmcnt, chunk-XOR swizzle, XCD swizzle)
template <int MODE, int WMF>
__global__ __launch_bounds__(256) void gemm_bt(
    const unsigned short* __restrict__ A, const unsigned short* __restrict__ Bt,
    unsigned short* __restrict__ Qo, unsigned short* __restrict__ Ko,
    unsigned short* __restrict__ Vo, float* __restrict__ out,
    const float* __restrict__ bo) {
  constexpr int K = 1024;
  constexpr int BM = WMF * 32;
  constexpr int NW = K / 64;                    // 16 windows of 2 subtiles
  constexpr int ASZ = BM * 32;
  constexpr int BSZ = 128 * 32;
  __shared__ __align__(16) unsigned short smem[4 * ASZ + 4 * BSZ];
  unsigned short* Asb = smem;
  unsigned short* Bsb = smem + 4 * ASZ;
  const int t = threadIdx.x;
  const int lane = t & 63;
  const int w = t >> 6;
  const int lr = lane & 15, kf = lane >> 4;
  const int wr = w >> 1, wc = w & 1;

  const int nwg = gridDim.x * gridDim.y;
  const int id = blockIdx.y * gridDim.x + blockIdx.x;
  const int swz = (id & 7) * (nwg >> 3) + (id >> 3);
  const int bx = swz % gridDim.x, by = swz / gridDim.x;

  const int rowbase = bx * BM;
  const int colbase = by * 128;

  const unsigned short* Ab = A + (size_t)rowbase * K;
  const unsigned short* Bb = Bt + (size_t)colbase * K;

  f32x4 acc[WMF][4];
#pragma unroll
  for (int m = 0; m < WMF; m++)
#pragma unroll
    for (int n = 0; n < 4; n++) acc[m][n] = zero4();

  auto stage = [&](int buf, int wi) {
#pragma unroll
    for (int sub = 0; sub < 2; sub++) {
      int k0 = (2 * wi + sub) * 32;
      unsigned short* Ad = Asb + ((size_t)buf * 2 + sub) * ASZ;
      unsigned short* Bd = Bsb + ((size_t)buf * 2 + sub) * BSZ;
#pragma unroll
      for (int i = 0; i < BM / 64; i++) {
        int f = i * 256 + t;
        int c = f ^ ((f >> 3) & 3);
        int row = c >> 2;
        int col = (c & 3) << 3;
        async16(Ab + (size_t)row * K + k0 + col, (char*)Ad + (size_t)f * 16);
      }
#pragma unroll
      for (int i = 0; i < 2; i++) {
        int f = i * 256 + t;
        int c = f ^ ((f >> 3) & 3);
        int row = c >> 2;
        int col = (c & 3) << 3;
        async16(Bb + (size_t)row * K + k0 + col, (char*)Bd + (size_t)f * 16);
      }
    }
  };

  auto compute = [&](int buf, int sub) {
    const unsigned short* As = Asb + ((size_t)buf * 2 + sub) * ASZ;
    const unsigned short* Bs = Bsb + ((size_t)buf * 2 + sub) * BSZ;
    short8 av[WMF], bv[4];
#pragma unroll
    for (int m = 0; m < WMF; m++) {
      int row = wr * (WMF * 16) + m * 16 + lr;
      int idx = (row * 32 + kf * 8) ^ (((row >> 1) & 3) << 3);
      av[m] = *(const short8*)&As[idx];
    }
#pragma unroll
    for (int n = 0; n < 4; n++) {
      int row = wc * 64 + n * 16 + lr;
      int idx = (row * 32 + kf * 8) ^ (((row >> 1) & 3) << 3);
      bv[n] = *(const short8*)&Bs[idx];
    }
    __builtin_amdgcn_s_setprio(1);
#pragma unroll
    for (int m = 0; m < WMF; m++)
#pragma unroll
      for (int n = 0; n < 4; n++) acc[m][n] = MFMA16(av[m], bv[n], acc[m][n]);
    __builtin_amdgcn_s_setprio(0);
  };

  stage(0, 0);
  int cur = 0;

  for (int wi = 0; wi < NW; wi++) {
    if (wi + 1 < NW) {
      stage(cur ^ 1, wi + 1);
      if constexpr (MODE == 0) asm volatile("s_waitcnt vmcnt(8)" ::: "memory");
      else                     asm volatile("s_waitcnt vmcnt(6)" ::: "memory");
    } else {
      asm volatile("s_waitcnt vmcnt(0)" ::: "memory");
    }
    __builtin_amdgcn_s_barrier();

    compute(cur, 0);
    compute(cur, 1);

    __builtin_amdgcn_s_barrier();
    cur ^= 1;
  }

  // Epilogue. C/D layout: col = lane&15, row = (lane>>4)*4 + i  [m89-verified]
  if constexpr (MODE == 0) {
    if (colbase < 2048) {
      const int selq = colbase >> 10;              // 0=Q 1=K
      unsigned short* dst = selq ? Ko : Qo;
      const float sc = selq ? 1.0f : 0.18033688011112042f;  // 0.125*log2e into Q
#pragma unroll
      for (int n = 0; n < 4; n++) {
        int c = colbase + wc * 64 + n * 16 + lr;
        int hh = (c >> 6) & 15;
        int dd = c & 63;
#pragma unroll
        for (int m = 0; m < WMF; m++) {
          int r0 = rowbase + wr * (WMF * 16) + m * 16 + kf * 4;
#pragma unroll
          for (int i = 0; i < 4; i++) {
            int r = r0 + i;
            int bi = r >> 11;
            int tq = r & 2047;
            dst[((size_t)(bi * NH + hh) * SEQ + tq) * HD + dd] = f2bf(acc[m][n][i] * sc);
          }
        }
      }
    } else {
      // V block: transpose tile in LDS (dead pipeline buffers), store V^T coalesced.
      unsigned short* tr = smem;                   // [128 col][136]
#pragma unroll
      for (int n = 0; n < 4; n++) {
        int ccol = wc * 64 + n * 16 + lr;
#pragma unroll
        for (int m = 0; m < WMF; m++) {
#pragma unroll
          for (int i = 0; i < 4; i++) {
            int rrow = wr * (WMF * 16) + m * 16 + kf * 4 + i;
            tr[ccol * 136 + rrow] = f2bf(acc[m][n][i]);
          }
        }
      }
      __syncthreads();
      const int bi2 = rowbase >> 11;
      const int tq0 = rowbase & 2047;
#pragma unroll
      for (int k2 = 0; k2 < 8; k2++) {
        int u = k2 * 256 + t;
        int cc = u >> 4, seg = u & 15;
        int c = colbase + cc;
        int hh = (c >> 6) & 15, dd = c & 63;
        short8 v8 = *(const short8*)&tr[cc * 136 + seg * 8];
        *(short8*)&Vo[((size_t)(bi2 * NH + hh) * HD + dd) * SEQ + tq0 + seg * 8] = v8;
      }
    }
  } else {
#pragma unroll
    for (int n = 0; n < 4; n++) {
      int c = colbase + wc * 64 + n * 16 + lr;
      float bias = bo[c];
#pragma unroll
      for (int m = 0; m < WMF; m++) {
        int r0 = rowbase + wr * (WMF * 16) + m * 16 + kf * 4;
#pragma unroll
        for (int i = 0; i < 4; i++) {
          out[(size_t)(r0 + i) * 1024 + c] = acc[m][n][i] + bias;
        }
      }
    }
  }
}

// ---------------- flash attention (uniform blocks: 2 q-tiles, 2 wave groups) ----------------
// grid: x = b*H (32), y = 0..7. Block q-tiles: a = 15-y (heavy), b = y (light).
// 512 thr = 8 waves = 2 groups of 4. Group 0: tile a pairs 0..7. Group 1: tile b
// pairs 0..y then tile a pairs 8..15-y. 9 windows each, perfectly uniform.
// Tile-a partials summed in-block via LDS (static softmax: O,l additive).
__global__ __launch_bounds__(512) void attn_fwd(
    const unsigned short* __restrict__ Q, const unsigned short* __restrict__ K,
    const unsigned short* __restrict__ Vt, unsigned short* __restrict__ ctx) {
  const int bh = blockIdx.x;
  const int y = blockIdx.y;                     // 0..7
  const int qa = 15 - y, qb = y;
  const int bi = bh >> 4, hh = bh & 15;
  const int t = threadIdx.x, lane = t & 63, w = t >> 6;
  const int g = w >> 2, wl = w & 3, tg = t & 255;
  const int qc = lane & 31, hi = lane >> 5;

  // [group][dbuf][sub]
  __shared__ __align__(16) unsigned short Ks[2][2][2][4096];
  __shared__ __align__(16) unsigned short Vs[2][2][2][4096];

  const unsigned short* Qb = Q + (size_t)bh * SEQ * HD;
  const unsigned short* Kb = K + (size_t)bh * SEQ * HD;
  const unsigned short* Vb = Vt + (size_t)bh * HD * SEQ;

  const int qrowA = qa * 128 + wl * 32;
  const int qrowB = qb * 128 + wl * 32;
  const int ktmaxA = 2 * qa + (wl >> 1);
  const int ktmaxB = 2 * qb + (wl >> 1);

  short8 qvA[4], qvB[4];
#pragma unroll
  for (int c = 0; c < 4; c++)
    qvA[c] = *(const short8*)&Qb[(size_t)(qrowA + qc) * HD + c * 16 + hi * 8];
  if (g == 1) {
#pragma unroll
    for (int c = 0; c < 4; c++)
      qvB[c] = *(const short8*)&Qb[(size_t)(qrowB + qc) * HD + c * 16 + hi * 8];
  }

  f32x16 oA0, oA1, oB0, oB1;
#pragma unroll
  for (int i = 0; i < 16; i++) { oA0[i] = 0.f; oA1[i] = 0.f; oB0[i] = 0.f; oB1[i] = 0.f; }
  float lA = 0.f, lB = 0.f;

  // window i -> (useB, pair). Group 0: tile a pairs 0..7, idle at i=8.
  // Group 1: i<=y: tile b pair i; else tile a pair 8+(i-y-1).
  auto pairAt = [&](int i, bool& useB, int& p) -> bool {
    if (g == 0) { useB = false; p = i; return i < 8; }
    if (i <= qb) { useB = true; p = i; return true; }
    useB = false; p = 8 + (i - qb - 1); return true;
  };

  // stage k-pair p (k-tiles 2p, 2p+1) into this group's dbuf buf (chunk-XOR swizzle)
  auto stage = [&](int buf, int p) {
#pragma unroll
    for (int sub = 0; sub < 2; sub++) {
      int kt = 2 * p + sub;
#pragma unroll
      for (int i2 = 0; i2 < 2; i2++) {
        int f = i2 * 256 + tg;
        int c = f ^ ((f >> 3) & 7);
        async16(Kb + (size_t)kt * 64 * HD + (size_t)c * 8,
                (char*)&Ks[g][buf][sub][0] + (size_t)f * 16);
        int d = c >> 3, ko = (c & 7) << 3;
        async16(Vb + (size_t)d * SEQ + (size_t)kt * 64 + ko,
                (char*)&Vs[g][buf][sub][0] + (size_t)f * 16);
      }
    }
  };

  auto qk = [&](const unsigned short* Kt, const short8* qv, f32x16& s0, f32x16& s1) {
#pragma unroll
    for (int i = 0; i < 16; i++) { s0[i] = 0.f; s1[i] = 0.f; }
    __builtin_amdgcn_s_setprio(1);
#pragma unroll
    for (int c = 0; c < 4; c++) {
      int i0 = (qc * 64 + c * 16 + hi * 8) ^ ((qc & 7) << 3);
      s0 = MFMA32(*(const short8*)&Kt[i0], qv[c], s0);
      int r1 = 32 + qc;
      int i1 = (r1 * 64 + c * 16 + hi * 8) ^ ((r1 & 7) << 3);
      s1 = MFMA32(*(const short8*)&Kt[i1], qv[c], s1);
    }
    __builtin_amdgcn_s_setprio(0);
  };

  auto maskit = [&](f32x16& s0, f32x16& s1, int kt, int qrow) {
    const int qg = qrow + qc;
#pragma unroll
    for (int reg = 0; reg < 16; reg++) {
      int rloc = (reg & 3) + 8 * (reg >> 2) + 4 * hi;
      int kg = kt * 64 + rloc;
      if (kg > qg) s0[reg] = -1e30f;
      if (kg + 32 > qg) s1[reg] = -1e30f;
    }
  };

  auto smpack = [&](const f32x16& s0, const f32x16& s1, unsigned* w0, unsigned* w1,
                    float& lacc) {
    float psA = 0.f, psB = 0.f;
#pragma unroll
    for (int j = 0; j < 8; j++) {
      float a0 = exp2x(s0[2 * j]), b0 = exp2x(s0[2 * j + 1]);
      float a1 = exp2x(s1[2 * j]), b1 = exp2x(s1[2 * j + 1]);
      psA += a0 + b0;
      psB += a1 + b1;
      w0[j] = cvt_pk(a0, b0);
      w1[j] = cvt_pk(a1, b1);
    }
    lacc += psA + psB;
  };

  auto pv = [&](const unsigned short* Vtile, unsigned* w0, unsigned* w1,
                f32x16& o0, f32x16& o1) {
    __builtin_amdgcn_s_setprio(1);
#pragma unroll
    for (int h2 = 0; h2 < 2; h2++) {
      unsigned* pw = h2 ? w1 : w0;
#pragma unroll
      for (int cc = 0; cc < 2; cc++) {
        unsigned a0 = pw[cc * 4 + 0], b0 = pw[cc * 4 + 2];
        unsigned a1 = pw[cc * 4 + 1], b1 = pw[cc * 4 + 3];
        pls(a0, b0);
        pls(a1, b1);
        u32x4 pf; pf[0] = a0; pf[1] = a1; pf[2] = b0; pf[3] = b1;
        short8 pfrag = as_short8(pf);
        int c2 = h2 * 2 + cc;
        int ia = (qc * 64 + c2 * 16 + hi * 8) ^ ((qc & 7) << 3);
        o0 = MFMA32(*(const short8*)&Vtile[ia], pfrag, o0);
        int rb = 32 + qc;
        int ib = (rb * 64 + c2 * 16 + hi * 8) ^ ((rb & 7) << 3);
        o1 = MFMA32(*(const short8*)&Vtile[ib], pfrag, o1);
      }
    }
    __builtin_amdgcn_s_setprio(0);
  };

  auto do_pair = [&](int cur, int p, const short8* qv, int ktmax, int qrow,
                     f32x16& o0, f32x16& o1, float& lacc) {
    const bool v0 = (2 * p <= ktmax);
    const bool v1 = (2 * p + 1 <= ktmax);
    f32x16 sA0, sA1, sB0, sB1;
    if (v0) qk(&Ks[g][cur][0][0], qv, sA0, sA1);
    if (v1) qk(&Ks[g][cur][1][0], qv, sB0, sB1);
    if (v0 && 2 * p == ktmax)     maskit(sA0, sA1, 2 * p, qrow);
    if (v1 && 2 * p + 1 == ktmax) maskit(sB0, sB1, 2 * p + 1, qrow);
    unsigned w0A[8], w1A[8], w0B[8], w1B[8];
    if (v0) smpack(sA0, sA1, w0A, w1A, lacc);
    if (v1) smpack(sB0, sB1, w0B, w1B, lacc);
    if (v0) pv(&Vs[g][cur][0][0], w0A, w1A, o0, o1);
    if (v1) pv(&Vs[g][cur][1][0], w0B, w1B, o0, o1);
  };

  {
    bool ub; int p0;
    if (pairAt(0, ub, p0)) stage(0, p0);
  }
  int cur = 0;

  for (int i = 0; i < 9; i++) {
    bool ubn; int pn;
    const bool hasn = (i + 1 < 9) && pairAt(i + 1, ubn, pn);
    if (hasn) {
      stage(cur ^ 1, pn);
      asm volatile("s_waitcnt vmcnt(8)" ::: "memory");
    } else {
      asm volatile("s_waitcnt vmcnt(0)" ::: "memory");
    }
    __builtin_amdgcn_s_barrier();

    bool ub; int p;
    if (pairAt(i, ub, p)) {
      if (ub) do_pair(cur, p, qvB, ktmaxB, qrowB, oB0, oB1, lB);
      else    do_pair(cur, p, qvA, ktmaxA, qrowA, oA0, oA1, lA);
    }

    __builtin_amdgcn_s_barrier();
    cur ^= 1;
  }

  // ---- epilogue ----
  // exchange region (overlays Ks): ex[128 rows][65] f32 + lex[128]
  float* ex = (float*)&Ks[0][0][0][0];
  float* lex = ex + 128 * 65;

  float lApart = lA + __shfl_xor(lA, 32);

  __builtin_amdgcn_s_barrier();    // staging LDS dead
  if (g == 1) {
    const int row = wl * 32 + qc;
#pragma unroll
    for (int gi = 0; gi < 4; gi++) {
#pragma unroll
      for (int jj = 0; jj < 4; jj++) {
        ex[row * 65 + 8 * gi + 4 * hi + jj] = oA0[4 * gi + jj];
        ex[row * 65 + 32 + 8 * gi + 4 * hi + jj] = oA1[4 * gi + jj];
      }
    }
    if (hi == 0) lex[row] = lApart;
  }
  __builtin_amdgcn_s_barrier();

  if (g == 0) {
    // combine tile-a halves, divide, write ctx rows of tile a
    const int row = wl * 32 + qc;
#pragma unroll
    for (int gi = 0; gi < 4; gi++) {
#pragma unroll
      for (int jj = 0; jj < 4; jj++) {
        oA0[4 * gi + jj] += ex[row * 65 + 8 * gi + 4 * hi + jj];
        oA1[4 * gi + jj] += ex[row * 65 + 32 + 8 * gi + 4 * hi + jj];
      }
    }
    float l = lApart + lex[row];
    float inv = 1.0f / l;
    const size_t rowoff = ((size_t)bi * SEQ + qrowA + qc) * DMODEL + hh * HD;
#pragma unroll
    for (int gi = 0; gi < 4; gi++) {
      unsigned pa = cvt_pk(oA0[4 * gi] * inv, oA0[4 * gi + 1] * inv);
      unsigned pb = cvt_pk(oA0[4 * gi + 2] * inv, oA0[4 * gi + 3] * inv);
      uint2 vv; vv.x = pa; vv.y = pb;
      *(uint2*)&ctx[rowoff + 8 * gi + 4 * hi] = vv;
      unsigned pc = cvt_pk(oA1[4 * gi] * inv, oA1[4 * gi + 1] * inv);
      unsigned pd = cvt_pk(oA1[4 * gi + 2] * inv, oA1[4 * gi + 3] * inv);
      uint2 ww; ww.x = pc; ww.y = pd;
      *(uint2*)&ctx[rowoff + 32 + 8 * gi + 4 * hi] = ww;
    }
  } else {
    // tile b is complete in this group: divide, write ctx rows of tile b
    float l = lB + __shfl_xor(lB, 32);
    float inv = 1.0f / l;
    const size_t rowoff = ((size_t)bi * SEQ + qrowB + qc) * DMODEL + hh * HD;
#pragma unroll
    for (int gi = 0; gi < 4; gi++) {
      unsigned pa = cvt_pk(oB0[4 * gi] * inv, oB0[4 * gi + 1] * inv);
      unsigned pb = cvt_pk(oB0[4 * gi + 2] * inv, oB0[4 * gi + 3] * inv);
      uint2 vv; vv.x = pa; vv.y = pb;
      *(uint2*)&ctx[rowoff + 8 * gi + 4 * hi] = vv;
      unsigned pc = cvt_pk(oB1[4 * gi] * inv, oB1[4 * gi + 1] * inv);
      unsigned pd = cvt_pk(oB1[4 * gi + 2] * inv, oB1[4 * gi + 3] * inv);
      uint2 ww; ww.x = pc; ww.y = pd;
      *(uint2*)&ctx[rowoff + 32 + 8 * gi + 4 * hi] = ww;
    }
  }
}

// ---------------- launch ----------------
extern "C" void kernel_launch(void* const* d_in, const int* in_sizes, int n_in,
                              void* d_out, int out_size, void* d_ws, size_t ws_size,
                              hipStream_t stream) {
  const float* x  = (const float*)d_in[0];
  const float* Wq = (const float*)d_in[1];
  const float* Wk = (const float*)d_in[2];
  const float* Wv = (const float*)d_in[3];
  const float* Wo = (const float*)d_in[4];
  const float* bo = (const float*)d_in[5];
  float* out = (float*)d_out;

  unsigned short* xb   = (unsigned short*)d_ws;                 // 4M elems
  unsigned short* Wt   = xb + (size_t)MROWS * DMODEL;           // 3M (Wq^T|Wk^T|Wv^T)
  unsigned short* WoT  = Wt + (size_t)3 * 1024 * 1024;          // 1M
  unsigned short* Qb   = WoT + (size_t)1024 * 1024;             // 4M
  unsigned short* Kb   = Qb + (size_t)MROWS * DMODEL;           // 4M
  unsigned short* Vb   = Kb + (size_t)MROWS * DMODEL;           // 4M  V^T [b,h,d,t]
  unsigned short* ctxb = Vb + (size_t)MROWS * DMODEL;           // 4M

  prep<<<3072, 256, 0, stream>>>(x, Wq, Wk, Wv, Wo, xb, Wt, WoT);

  gemm_bt<0, 4><<<dim3(32, 24), 256, 0, stream>>>(xb, Wt, Qb, Kb, Vb, nullptr, nullptr);
  attn_fwd<<<dim3(32, 8), 512, 0, stream>>>(Qb, Kb, Vb, ctxb);
  gemm_bt<1, 2><<<dim3(64, 8), 256, 0, stream>>>(ctxb, WoT, nullptr, nullptr, nullptr, out, bo);
}